// Round 10
// baseline (361.186 us; speedup 1.0000x reference)
//
#include <hip/hip_runtime.h>
#include <hip/hip_bf16.h>

// Shapes: B=64 S=32 H=40 W=64 ; conv1: 1->32 (20x32) ; conv2: 32->64 (10x16) ; conv3: 64->32 (5x8)
// SENS=1283 UNITS=48 MOTOR=4 NA=2 UNFOLDS=6

typedef __attribute__((ext_vector_type(8))) short bshort8;   // 8 bf16 (4 VGPR) MFMA frag
typedef __attribute__((ext_vector_type(4))) float f32x4;     // MFMA acc

// ---- workspace layout (float units) ----
constexpr long OFF_SEQ  = 0;                 // 2048*1283 = 2627584
constexpr long OFF_SP4  = 2627584;           // sensory params float4[1283*48] = 246336 fl
constexpr long OFF_RP4  = 2873920;           // rec params float4[48*64] = 12288 fl
constexpr long OFF_CM   = 2886208;           // cm_t(64), gl(64), gl*vleak(64)
constexpr long OFF_W2B  = 2886400;           // conv2 bf16 frags: 18432 bf16 = 9216 fl
constexpr long OFF_W3B  = 2895616;           // conv3 bf16 frags: 18432 bf16 = 9216 fl
constexpr long OFF_PART = 2904832;           // float2[2048*48] = 196608 fl
// end 3101440 fl = 12.41 MB

__device__ __forceinline__ float sp_(float x) {
    return fmaxf(x, 0.f) + log1pf(expf(-fabsf(x)));   // stable softplus
}

// ---------------------------------------------------------------------------
// prep (R9-verbatim)
// ---------------------------------------------------------------------------
__global__ void prep_kernel(const float* __restrict__ sens_w, const float* __restrict__ sens_mu,
                            const float* __restrict__ sens_sigma, const float* __restrict__ sens_erev,
                            const int* __restrict__ sens_mask,
                            const float* __restrict__ rec_w, const float* __restrict__ rec_mu,
                            const float* __restrict__ rec_sigma, const float* __restrict__ rec_erev,
                            const int* __restrict__ rec_mask,
                            const float* __restrict__ gleak, const float* __restrict__ vleak,
                            const float* __restrict__ cm,
                            const float* __restrict__ w2, const float* __restrict__ w3,
                            float* __restrict__ ws) {
    const float L2E = 1.4426950408889634f;
    int i = blockIdx.x * 256 + threadIdx.x;
    if (i < 61584) {                       // sensory packed [k 1283][u 48]
        float m  = sens_mask[i] ? 1.f : 0.f;
        float sw = sp_(sens_w[i]) * m;
        float sg = sens_sigma[i], mu = sens_mu[i];
        ((float4*)(ws + OFF_SP4))[i] =
            make_float4(-sg * L2E, sg * mu * L2E, sw * sens_erev[i], sw);
    } else if (i < 64656) {                // recurrent: [j 48][u 64 padded]
        int q = i - 61584;
        int j = q >> 6, u = q & 63;
        float4 v = make_float4(0.f, 0.f, 0.f, 0.f);
        if (u < 48) {
            int idx = j * 48 + u;
            float m  = rec_mask[idx] ? 1.f : 0.f;
            float sw = sp_(rec_w[idx]) * m;
            float sg = rec_sigma[idx], mu = rec_mu[idx];
            v = make_float4(-sg * L2E, sg * mu * L2E, sw * rec_erev[idx], sw);
        }
        ((float4*)(ws + OFF_RP4))[q] = v;
    } else if (i < 64704) {
        int u = i - 64656;                 // u < 48
        float g = sp_(gleak[u]);
        ws[OFF_CM + u]       = sp_(cm[u]) * 6.f;
        ws[OFF_CM + 64 + u]  = g;
        ws[OFF_CM + 128 + u] = g * vleak[u];
    } else if (i < 83136) {                // w2b frags
        int n = i - 64704;
        int j = n & 7, l = (n >> 3) & 63, t2 = n >> 9;
        int wv = t2 & 3, p = t2 >> 2;
        int ky = p / 3, kx = p % 3;
        int oc = wv * 16 + (l & 15);
        int ic = (l >> 4) * 8 + j;
        ((__hip_bfloat16*)(ws + OFF_W2B))[n] =
            __float2bfloat16(w2[((oc * 32 + ic) * 3 + ky) * 3 + kx]);
    } else if (i < 101568) {               // w3b frags
        int n = i - 83136;
        int j = n & 7, l = (n >> 3) & 63, t3 = n >> 9;
        int h = t3 & 1, u2 = t3 >> 1;
        int nt = u2 / 9, p = u2 % 9;
        int ky = p / 3, kx = p % 3;
        int oc = nt * 16 + (l & 15);
        int ic = h * 32 + (l >> 4) * 8 + j;
        ((__hip_bfloat16*)(ws + OFF_W3B))[n] =
            __float2bfloat16(w3[((oc * 64 + ic) * 3 + ky) * 3 + kx]);
    }
}

// ---------------------------------------------------------------------------
// Fused CNN — R9-verbatim except conv1 px-loop unroll 1 -> 2 (overlap the
// ds_read batches of adjacent pixel iterations; no layout change).
// ---------------------------------------------------------------------------
#define IMGB 0
#define C1E  5412
#define C1O  28260
#define A2E  0
#define A2O  12672
#define SMB  51120

__global__ __launch_bounds__(256, 3) void cnn_kernel(
    const float* __restrict__ depth, const float* __restrict__ relpos,
    const float* __restrict__ w1, const float* __restrict__ b1,
    const float* __restrict__ b2, const float* __restrict__ b3,
    const __hip_bfloat16* __restrict__ w2b, const __hip_bfloat16* __restrict__ w3b,
    float* __restrict__ seq) {
    __shared__ __align__(16) char smraw[SMB];
    const int t = threadIdx.x;
    const int img = blockIdx.x;
    const int l = t & 63;
    const int wvu = __builtin_amdgcn_readfirstlane(t >> 6);
    const int m = l & 15, kg = l >> 4;

    bshort8 Bf[9];
#pragma unroll
    for (int p = 0; p < 9; ++p)
        Bf[p] = *(const bshort8*)(w2b + ((p * 4 + wvu) * 64 + l) * 8);

    for (int i = t; i < 12777; i += 256) ((uint*)smraw)[i] = 0u;
    __syncthreads();
    for (int i = t; i < 1280; i += 256) {
        int pos = 2 * i;
        int h = pos >> 6, w = pos & 63;
        float2 d = *(const float2*)(depth + (long)img * 2560 + pos);
        __hip_bfloat162 pk = __float22bfloat162_rn(d);
        *(__hip_bfloat162*)(smraw + IMGB + ((h + 1) * 66 + (w + 2)) * 2) = pk;
    }
    __syncthreads();

    // ---- conv1: wave wvu -> oc groups {wvu, wvu+4}, 10 px/lane, unroll 2 ----
    const __hip_bfloat16* imgp = (const __hip_bfloat16*)(smraw + IMGB);
#pragma unroll 1
    for (int pc = 0; pc < 2; ++pc) {
        const int g = wvu + 4 * pc;          // uniform 0..7: oc = g*4 .. g*4+3
        const int q1 = g >> 1;
        const int sub = (g & 1) * 4;
        float wv[4][9], bv[4];
#pragma unroll
        for (int j = 0; j < 4; ++j) {
            bv[j] = b1[g * 4 + j];
#pragma unroll
            for (int k = 0; k < 9; ++k) wv[j][k] = w1[(g * 4 + j) * 9 + k];
        }
#pragma unroll 2
        for (int i = 0; i < 10; ++i) {
            int p = l + (i << 6);
            int y1 = p >> 5, x1 = p & 31;
            float xin[9];
#pragma unroll
            for (int ky = 0; ky < 3; ++ky)
#pragma unroll
                for (int kx = 0; kx < 3; ++kx)
                    xin[ky * 3 + kx] = __bfloat162float(imgp[(2 * y1 + ky) * 66 + 2 * x1 + kx + 1]);
            float o[4];
#pragma unroll
            for (int j = 0; j < 4; ++j) {
                float a = bv[j];
#pragma unroll
                for (int k = 0; k < 9; ++k) a = fmaf(wv[j][k], xin[k], a);
                o[j] = fmaxf(a, 0.f);
            }
            int odd = x1 & 1;
            int xi = odd ? ((x1 + 1) >> 1) : (x1 >> 1);
            char* cb = smraw + (odd ? C1O : C1E) +
                       (((q1 * 21 + (y1 + 1)) * 17 + xi) * 8 + sub) * 2;
            *(__hip_bfloat162*)cb       = __float22bfloat162_rn(make_float2(o[0], o[1]));
            *(__hip_bfloat162*)(cb + 4) = __float22bfloat162_rn(make_float2(o[2], o[3]));
        }
    }
    __syncthreads();

    // ---- conv2 (verbatim): 10 M-tiles x wave's 16 oc ----
    f32x4 acc[10];
    {
        float bias = b2[wvu * 16 + m];
#pragma unroll
        for (int mt = 0; mt < 10; ++mt) acc[mt] = (f32x4){bias, bias, bias, bias};
    }
#pragma unroll
    for (int ky = 0; ky < 3; ++ky) {
#pragma unroll
        for (int kx = 0; kx < 3; ++kx) {
            const char* arr = smraw + ((kx == 1) ? C1E : C1O);
            int xi = m + (kx == 2);
            const char* base = arr + ((kg * 21 + ky) * 17 + xi) * 16;
            bshort8 Bp = Bf[ky * 3 + kx];
#pragma unroll
            for (int mt = 0; mt < 10; ++mt) {
                bshort8 A = *(const bshort8*)(base + mt * 544);
                acc[mt] = __builtin_amdgcn_mfma_f32_16x16x32_bf16(A, Bp, acc[mt], 0, 0, 0);
            }
        }
    }
    __syncthreads();

    for (int i = t; i < 6336; i += 256) ((uint*)smraw)[i] = 0u;
    __syncthreads();
    {
        int oc = wvu * 16 + m;
        int q = oc >> 3, sub = oc & 7;
#pragma unroll
        for (int mt = 0; mt < 10; ++mt) {
            int row = mt + 1;
#pragma unroll
            for (int reg = 0; reg < 4; ++reg) {
                int x2 = kg * 4 + reg;
                int odd = x2 & 1;
                int xi = odd ? ((x2 + 1) >> 1) : (x2 >> 1);
                char* ab = smraw + (odd ? A2O : A2E);
                float v = fmaxf(acc[mt][reg], 0.f);
                *(__hip_bfloat16*)(ab + (((q * 11 + row) * 9 + xi) * 8 + sub) * 2) = __float2bfloat16(v);
            }
        }
    }
    __syncthreads();

    {
        const int nt = wvu & 1;
        const bool two = wvu < 2;
        f32x4 c3a = (f32x4){0.f, 0.f, 0.f, 0.f};
        f32x4 c3b = (f32x4){0.f, 0.f, 0.f, 0.f};
        const int xb = m & 7, yb = m >> 3;
#pragma unroll
        for (int p = 0; p < 9; ++p) {
            int ky = p / 3, kx = p % 3;
            const char* arr = smraw + ((kx == 1) ? A2E : A2O);
            int xi3 = xb + (kx == 2);
#pragma unroll
            for (int h = 0; h < 2; ++h) {
                bshort8 B = *(const bshort8*)(w3b + (((nt * 9 + p) * 2 + h) * 64 + l) * 8);
                int q = h * 4 + kg;
                const char* base = arr + ((q * 11 + 2 * yb + ky) * 9 + xi3) * 16;
                if (two) {
                    bshort8 A0 = *(const bshort8*)(base);
                    c3a = __builtin_amdgcn_mfma_f32_16x16x32_bf16(A0, B, c3a, 0, 0, 0);
                    bshort8 A2 = *(const bshort8*)(base + 1152);
                    c3b = __builtin_amdgcn_mfma_f32_16x16x32_bf16(A2, B, c3b, 0, 0, 0);
                } else {
                    bshort8 A1 = *(const bshort8*)(base + 576);
                    c3a = __builtin_amdgcn_mfma_f32_16x16x32_bf16(A1, B, c3a, 0, 0, 0);
                }
            }
        }
        __syncthreads();
        float* sb = (float*)smraw;
        int oc = nt * 16 + m;
        float bv = b3[oc];
        int ob40 = oc * 40;
        if (two) {
#pragma unroll
            for (int reg = 0; reg < 4; ++reg) {
                sb[ob40 + kg * 4 + reg] = fmaxf(c3a[reg] + bv, 0.f);
                int px2 = 32 + kg * 4 + reg;
                if (px2 < 40) sb[ob40 + px2] = fmaxf(c3b[reg] + bv, 0.f);
            }
        } else {
#pragma unroll
            for (int reg = 0; reg < 4; ++reg)
                sb[ob40 + 16 + kg * 4 + reg] = fmaxf(c3a[reg] + bv, 0.f);
        }
        __syncthreads();
        for (int i = t; i < 1283; i += 256)
            seq[(long)img * 1283 + i] = (i < 1280) ? sb[i] : relpos[img * 3 + (i - 1280)];
    }
}

// ---------------------------------------------------------------------------
// Sensory synapse sums, regridded for occupancy: 512 blocks x 384 threads,
// 4 pairs/block, FULL k-range per block (no partial merge, no atomics).
// LDS 20.6 KB time-shared (IT [1283][4] -> red [8][4][48]) => 5 blocks/CU.
// Param array (985 KB) is L2-resident; 504 MB aggregate / 34.5 TB/s ~= 15 us.
// ---------------------------------------------------------------------------
__global__ __launch_bounds__(384) void sensory_kernel(
    const float* __restrict__ sp, const float* __restrict__ seq,
    const float* __restrict__ iw, const float* __restrict__ ibias,
    float2* __restrict__ part) {
    const float4* P4 = (const float4*)sp;
    __shared__ __align__(16) char sbuf[20544];
    float*  IT  = (float*)sbuf;        // [k][4 pairs], 20528 B
    float2* red = (float2*)sbuf;       // [(kg*4+p)*48+u], 12288 B, after barrier
    const int t = threadIdx.x;
    const int pb = blockIdx.x * 4;

    for (int p = 0; p < 4; ++p)
        for (int k = t; k < 1283; k += 384)
            IT[k * 4 + p] = fmaf(seq[(long)(pb + p) * 1283 + k], iw[k], ibias[k]);
    __syncthreads();

    const int u = t % 48, kg = t / 48;   // kg in 0..7
    float2 acc[4];
#pragma unroll
    for (int p = 0; p < 4; ++p) acc[p] = make_float2(0.f, 0.f);

#pragma unroll 2
    for (int i = 0; i < 161; ++i) {
        int k = kg + 8 * i;
        if (k < 1283) {
            float4 pv = P4[k * 48 + u];          // {A,B,WE,W}
            float4 Iv = *(const float4*)&IT[k * 4];
            float r0 = __builtin_amdgcn_rcpf(1.f + __builtin_amdgcn_exp2f(fmaf(pv.x, Iv.x, pv.y)));
            float r1 = __builtin_amdgcn_rcpf(1.f + __builtin_amdgcn_exp2f(fmaf(pv.x, Iv.y, pv.y)));
            float r2 = __builtin_amdgcn_rcpf(1.f + __builtin_amdgcn_exp2f(fmaf(pv.x, Iv.z, pv.y)));
            float r3 = __builtin_amdgcn_rcpf(1.f + __builtin_amdgcn_exp2f(fmaf(pv.x, Iv.w, pv.y)));
            acc[0].x = fmaf(pv.z, r0, acc[0].x); acc[0].y = fmaf(pv.w, r0, acc[0].y);
            acc[1].x = fmaf(pv.z, r1, acc[1].x); acc[1].y = fmaf(pv.w, r1, acc[1].y);
            acc[2].x = fmaf(pv.z, r2, acc[2].x); acc[2].y = fmaf(pv.w, r2, acc[2].y);
            acc[3].x = fmaf(pv.z, r3, acc[3].x); acc[3].y = fmaf(pv.w, r3, acc[3].y);
        }
    }
    __syncthreads();                    // IT reads done; sbuf becomes red
#pragma unroll
    for (int p = 0; p < 4; ++p) red[(kg * 4 + p) * 48 + u] = acc[p];
    __syncthreads();
    if (t < 192) {
        int p = t / 48, uu = t - p * 48;
        float sn = 0.f, sd = 0.f;
#pragma unroll
        for (int g = 0; g < 8; ++g) {
            float2 rr = red[(g * 4 + p) * 48 + uu];
            sn += rr.x; sd += rr.y;
        }
        part[(long)(pb + p) * 48 + uu] = make_float2(sn, sd);
    }
}

// ---------------------------------------------------------------------------
// Recurrent (R9-verbatim): 64 blocks x 512 thr, v in regs, 1 barrier/unfold.
// ---------------------------------------------------------------------------
__global__ __launch_bounds__(512) void recurrent_kernel(
    const float* __restrict__ rp, const float* __restrict__ cmglv,
    const float2* __restrict__ part,
    const float* __restrict__ out_w, const float* __restrict__ out_b,
    const float* __restrict__ head_w, const float* __restrict__ head_b,
    float* __restrict__ outp) {
    const float4* RP4 = (const float4*)rp;
    __shared__ float2 WL[32 * 48];
    __shared__ float2 red[2][8][64];
    __shared__ float ym[4];
    const int t = threadIdx.x, b = blockIdx.x;
    const int u = t & 63;
    const int jg = __builtin_amdgcn_readfirstlane(t >> 6);
    const int j0 = jg * 6;
    const bool uval = u < 48;
    float4 rpj[6];
#pragma unroll
    for (int jj = 0; jj < 6; ++jj) rpj[jj] = RP4[(j0 + jj) * 64 + u];
    for (int i = t; i < 1536; i += 512) WL[i] = part[(long)b * 1536 + i];
    float cmt = 0.f, gl = 0.f, glv = 0.f;
    if (uval) { cmt = cmglv[u]; gl = cmglv[64 + u]; glv = cmglv[128 + u]; }
    float ow = 0.f, ob = 0.f;
    if (jg == 0 && u < 4) { ow = out_w[u]; ob = out_b[u]; }
    __syncthreads();

    float vn = 0.f;
    float yacc = 0.f;
    int buf = 0;
    for (int s = 0; s < 32; ++s) {
        float2 wnd = uval ? WL[s * 48 + u] : make_float2(0.f, 0.f);
#pragma unroll 1
        for (int unf = 0; unf < 6; ++unf) {
            float pn = 0.f, pd = 0.f;
#pragma unroll
            for (int jj = 0; jj < 6; ++jj) {
                float vj = __shfl(vn, j0 + jj, 64);
                float r = __builtin_amdgcn_rcpf(1.f + __builtin_amdgcn_exp2f(fmaf(rpj[jj].x, vj, rpj[jj].y)));
                pn = fmaf(rpj[jj].z, r, pn);
                pd = fmaf(rpj[jj].w, r, pd);
            }
            red[buf][jg][u] = make_float2(pn, pd);
            __syncthreads();
            float sn = 0.f, sd = 0.f;
#pragma unroll
            for (int g = 0; g < 8; ++g) {
                float2 rr = red[buf][g][u];
                sn += rr.x; sd += rr.y;
            }
            float num = fmaf(cmt, vn, glv) + sn + wnd.x;
            float den = cmt + gl + sd + wnd.y;
            vn = uval ? num / (den + 1e-8f) : 0.f;
            buf ^= 1;
        }
        if (jg == 0 && u < 4) yacc = fmaf(vn, ow, yacc) + ob;
    }
    if (jg == 0 && u < 4) ym[u] = yacc;
    __syncthreads();
    if (t < 2) {
        const float inv = 1.f / 32.f;
        float o = ym[0] * inv * head_w[t] + ym[1] * inv * head_w[2 + t] +
                  ym[2] * inv * head_w[4 + t] + ym[3] * inv * head_w[6 + t] + head_b[t];
        outp[b * 2 + t] = tanhf(o);
    }
}

extern "C" void kernel_launch(void* const* d_in, const int* in_sizes, int n_in,
                              void* d_out, int out_size, void* d_ws, size_t ws_size,
                              hipStream_t stream) {
    const float* depth      = (const float*)d_in[0];
    const float* relpos     = (const float*)d_in[1];
    const float* w1         = (const float*)d_in[2];
    const float* b1         = (const float*)d_in[3];
    const float* w2         = (const float*)d_in[4];
    const float* b2         = (const float*)d_in[5];
    const float* w3         = (const float*)d_in[6];
    const float* b3         = (const float*)d_in[7];
    const float* iw         = (const float*)d_in[8];
    const float* ibias      = (const float*)d_in[9];
    const float* sens_w     = (const float*)d_in[10];
    const float* sens_mu    = (const float*)d_in[11];
    const float* sens_sigma = (const float*)d_in[12];
    const float* sens_erev  = (const float*)d_in[13];
    const float* rec_w      = (const float*)d_in[14];
    const float* rec_mu     = (const float*)d_in[15];
    const float* rec_sigma  = (const float*)d_in[16];
    const float* rec_erev   = (const float*)d_in[17];
    const float* gleak      = (const float*)d_in[18];
    const float* vleak      = (const float*)d_in[19];
    const float* cm         = (const float*)d_in[20];
    const float* out_w      = (const float*)d_in[21];
    const float* out_b      = (const float*)d_in[22];
    const float* head_w     = (const float*)d_in[23];
    const float* head_b     = (const float*)d_in[24];
    const int*   sens_mask  = (const int*)d_in[25];
    const int*   rec_mask   = (const int*)d_in[26];

    float* ws  = (float*)d_ws;
    float* out = (float*)d_out;

    prep_kernel<<<477, 256, 0, stream>>>(sens_w, sens_mu, sens_sigma, sens_erev, sens_mask,
                                         rec_w, rec_mu, rec_sigma, rec_erev, rec_mask,
                                         gleak, vleak, cm, w2, w3, ws);
    cnn_kernel<<<2048, 256, 0, stream>>>(depth, relpos, w1, b1, b2, b3,
                                         (const __hip_bfloat16*)(ws + OFF_W2B),
                                         (const __hip_bfloat16*)(ws + OFF_W3B),
                                         ws + OFF_SEQ);
    sensory_kernel<<<512, 384, 0, stream>>>(ws + OFF_SP4, ws + OFF_SEQ, iw, ibias,
                                            (float2*)(ws + OFF_PART));
    recurrent_kernel<<<64, 512, 0, stream>>>(ws + OFF_RP4, ws + OFF_CM,
                                             (const float2*)(ws + OFF_PART),
                                             out_w, out_b, head_w, head_b, out);
}

// Round 11
// 341.776 us; speedup vs baseline: 1.0568x; 1.0568x over previous
//
#include <hip/hip_runtime.h>
#include <hip/hip_bf16.h>

// Shapes: B=64 S=32 H=40 W=64 ; conv1: 1->32 (20x32) ; conv2: 32->64 (10x16) ; conv3: 64->32 (5x8)
// SENS=1283 UNITS=48 MOTOR=4 NA=2 UNFOLDS=6

typedef __attribute__((ext_vector_type(8))) short bshort8;   // 8 bf16 (4 VGPR) MFMA frag
typedef __attribute__((ext_vector_type(4))) float f32x4;     // MFMA acc

// ---- workspace layout (float units) ----
constexpr long OFF_SEQ  = 0;                 // 2048*1283 = 2627584
constexpr long OFF_SP4  = 2627584;           // sensory params float4[1283*48] = 246336 fl
constexpr long OFF_RP4  = 2873920;           // rec params float4[48*64] = 12288 fl
constexpr long OFF_CM   = 2886208;           // cm_t(64), gl(64), gl*vleak(64)
constexpr long OFF_W2B  = 2886400;           // conv2 bf16 frags (K-repacked): 24576 bf16 = 12288 fl
constexpr long OFF_W3B  = 2898688;           // conv3 bf16 frags: 18432 bf16 = 9216 fl
constexpr long OFF_PART = 2907904;           // float2[2048*48] = 196608 fl
// end 3104512 fl = 12.42 MB

__device__ __forceinline__ float sp_(float x) {
    return fmaxf(x, 0.f) + log1pf(expf(-fabsf(x)));   // stable softplus
}

// ---------------------------------------------------------------------------
// prep. w2b K-repack: K=32 = (x1off 2) x (ic-local 16); frag idx
// t2 = ((h*3+ky)*2+xp)*4+wv ; lane l: n=l&15 (oc), kgB=l>>4 ; k=kgB*8+j ->
// x1off=kgB>>1, icl=(kgB&1)*8+j ; kx=2*xp+x1off (kx==3 -> 0 weight).
// ---------------------------------------------------------------------------
__global__ void prep_kernel(const float* __restrict__ sens_w, const float* __restrict__ sens_mu,
                            const float* __restrict__ sens_sigma, const float* __restrict__ sens_erev,
                            const int* __restrict__ sens_mask,
                            const float* __restrict__ rec_w, const float* __restrict__ rec_mu,
                            const float* __restrict__ rec_sigma, const float* __restrict__ rec_erev,
                            const int* __restrict__ rec_mask,
                            const float* __restrict__ gleak, const float* __restrict__ vleak,
                            const float* __restrict__ cm,
                            const float* __restrict__ w2, const float* __restrict__ w3,
                            float* __restrict__ ws) {
    const float L2E = 1.4426950408889634f;
    int i = blockIdx.x * 256 + threadIdx.x;
    if (i < 61584) {                       // sensory packed [k 1283][u 48]
        float m  = sens_mask[i] ? 1.f : 0.f;
        float sw = sp_(sens_w[i]) * m;
        float sg = sens_sigma[i], mu = sens_mu[i];
        ((float4*)(ws + OFF_SP4))[i] =
            make_float4(-sg * L2E, sg * mu * L2E, sw * sens_erev[i], sw);
    } else if (i < 64656) {                // recurrent: [j 48][u 64 padded]
        int q = i - 61584;
        int j = q >> 6, u = q & 63;
        float4 v = make_float4(0.f, 0.f, 0.f, 0.f);
        if (u < 48) {
            int idx = j * 48 + u;
            float m  = rec_mask[idx] ? 1.f : 0.f;
            float sw = sp_(rec_w[idx]) * m;
            float sg = rec_sigma[idx], mu = rec_mu[idx];
            v = make_float4(-sg * L2E, sg * mu * L2E, sw * rec_erev[idx], sw);
        }
        ((float4*)(ws + OFF_RP4))[q] = v;
    } else if (i < 64704) {
        int u = i - 64656;                 // u < 48
        float g = sp_(gleak[u]);
        ws[OFF_CM + u]       = sp_(cm[u]) * 6.f;
        ws[OFF_CM + 64 + u]  = g;
        ws[OFF_CM + 128 + u] = g * vleak[u];
    } else if (i < 89280) {                // w2b K-repacked frags (24576)
        int n = i - 64704;
        int j = n & 7, l = (n >> 3) & 63, t2 = n >> 9;   // t2 0..47
        int wv = t2 & 3;
        int r  = t2 >> 2;                  // 0..11 = (h*3+ky)*2+xp
        int xp = r & 1, hk = r >> 1;       // hk = h*3+ky
        int ky = hk % 3, h = hk / 3;
        int oc = wv * 16 + (l & 15);
        int kgB = l >> 4;
        int icl = (kgB & 1) * 8 + j;
        int ic = h * 16 + icl;
        int kx = 2 * xp + (kgB >> 1);
        float val = (kx == 3) ? 0.f : w2[((oc * 32 + ic) * 3 + ky) * 3 + kx];
        ((__hip_bfloat16*)(ws + OFF_W2B))[n] = __float2bfloat16(val);
    } else if (i < 107712) {               // w3b frags (unchanged mapping)
        int n = i - 89280;
        int j = n & 7, l = (n >> 3) & 63, t3 = n >> 9;
        int h = t3 & 1, u2 = t3 >> 1;
        int nt = u2 / 9, p = u2 % 9;
        int ky = p / 3, kx = p % 3;
        int oc = nt * 16 + (l & 15);
        int ic = h * 32 + (l >> 4) * 8 + j;
        ((__hip_bfloat16*)(ws + OFF_W3B))[n] =
            __float2bfloat16(w3[((oc * 64 + ic) * 3 + ky) * 3 + kx]);
    }
}

// ---------------------------------------------------------------------------
// Fused CNN, channel-split conv1/conv2 (27.6 KB LDS -> 5 blocks/CU).
// LDS: img bf16 [41][66] @0 (5412 B) | c1h bf16 [21 row][34 col][16 ic] @5424
//      (22848 B, col = x1+1, col 33 = phantom-kx pad, always zero).
// Two passes h: conv1 writes ic-half h (16 ch), conv2 accumulates K-half.
// conv2 MFMA K=32 = 2 x-cols x 16 ic; A lane(m,kg): row=2mt+ky,
// col=2m+2xp+(kg>>1), ic-half=(kg&1). Full-region zeroing (pads persist).
// Phase C (a2 overlay + conv3 + epilogue) is R9-verbatim.
// ---------------------------------------------------------------------------
#define IMGB 0
#define C1H  5424
#define A2E  0
#define A2O  12672
#define SMB  28272

__global__ __launch_bounds__(256, 5) void cnn_kernel(
    const float* __restrict__ depth, const float* __restrict__ relpos,
    const float* __restrict__ w1, const float* __restrict__ b1,
    const float* __restrict__ b2, const float* __restrict__ b3,
    const __hip_bfloat16* __restrict__ w2b, const __hip_bfloat16* __restrict__ w3b,
    float* __restrict__ seq) {
    __shared__ __align__(16) char smraw[SMB];
    const int t = threadIdx.x;
    const int img = blockIdx.x;
    const int l = t & 63;
    const int wvu = __builtin_amdgcn_readfirstlane(t >> 6);
    const int m = l & 15, kg = l >> 4;

    // ---- zero ENTIRE img+c1h region (pads persist through both passes) ----
    for (int i = t; i < 7068; i += 256) ((uint*)smraw)[i] = 0u;
    __syncthreads();
    for (int i = t; i < 1280; i += 256) {
        int pos = 2 * i;
        int h = pos >> 6, w = pos & 63;
        float2 d = *(const float2*)(depth + (long)img * 2560 + pos);
        __hip_bfloat162 pk = __float22bfloat162_rn(d);
        *(__hip_bfloat162*)(smraw + IMGB + ((h + 1) * 66 + (w + 2)) * 2) = pk;
    }
    __syncthreads();

    const __hip_bfloat16* imgp = (const __hip_bfloat16*)(smraw + IMGB);
    f32x4 acc[10];
    {
        float bias = b2[wvu * 16 + m];
#pragma unroll
        for (int mt = 0; mt < 10; ++mt) acc[mt] = (f32x4){bias, bias, bias, bias};
    }

#pragma unroll 1
    for (int h = 0; h < 2; ++h) {
        // ---- conv1 pass h: 16 oc (wave wvu -> 4 oc), 10 px/lane ----
        const int ocb = h * 16 + wvu * 4;      // uniform
        float wv4[4][9], bv4[4];
#pragma unroll
        for (int j = 0; j < 4; ++j) {
            bv4[j] = b1[ocb + j];
#pragma unroll
            for (int k = 0; k < 9; ++k) wv4[j][k] = w1[(ocb + j) * 9 + k];
        }
#pragma unroll 1
        for (int i = 0; i < 10; ++i) {
            int p = l + (i << 6);
            int y1 = p >> 5, x1 = p & 31;
            float xin[9];
#pragma unroll
            for (int ky = 0; ky < 3; ++ky)
#pragma unroll
                for (int kx = 0; kx < 3; ++kx)
                    xin[ky * 3 + kx] = __bfloat162float(imgp[(2 * y1 + ky) * 66 + 2 * x1 + kx + 1]);
            float o[4];
#pragma unroll
            for (int j = 0; j < 4; ++j) {
                float a = bv4[j];
#pragma unroll
                for (int k = 0; k < 9; ++k) a = fmaf(wv4[j][k], xin[k], a);
                o[j] = fmaxf(a, 0.f);
            }
            char* cb = smraw + C1H + (((y1 + 1) * 34) + (x1 + 1)) * 32 + wvu * 8;
            *(__hip_bfloat162*)cb       = __float22bfloat162_rn(make_float2(o[0], o[1]));
            *(__hip_bfloat162*)(cb + 4) = __float22bfloat162_rn(make_float2(o[2], o[3]));
        }
        // ---- conv2 K-half h ----
        bshort8 Bh[6];
#pragma unroll
        for (int f = 0; f < 6; ++f)
            Bh[f] = *(const bshort8*)(w2b + (((h * 6 + f) * 4 + wvu) * 64 + l) * 8);
        __syncthreads();   // c1h pass-h ready
#pragma unroll
        for (int ky = 0; ky < 3; ++ky) {
#pragma unroll
            for (int xp = 0; xp < 2; ++xp) {
                bshort8 Bp = Bh[ky * 2 + xp];
                const char* base = smraw + C1H + (ky * 34 + 2 * m + 2 * xp + (kg >> 1)) * 32 + (kg & 1) * 16;
#pragma unroll
                for (int mt = 0; mt < 10; ++mt) {
                    bshort8 A = *(const bshort8*)(base + mt * 2176);   // 2 rows * 34 cols * 32 B
                    acc[mt] = __builtin_amdgcn_mfma_f32_16x16x32_bf16(A, Bp, acc[mt], 0, 0, 0);
                }
            }
        }
        __syncthreads();   // reads done before next conv1 overwrite / a2 overlay
    }

    // ---- a2 overlay (R9-verbatim): full zero, barrier, write, barrier ----
    for (int i = t; i < 6336; i += 256) ((uint*)smraw)[i] = 0u;
    __syncthreads();
    {
        int oc = wvu * 16 + m;
        int q = oc >> 3, sub = oc & 7;
#pragma unroll
        for (int mt = 0; mt < 10; ++mt) {
            int row = mt + 1;
#pragma unroll
            for (int reg = 0; reg < 4; ++reg) {
                int x2 = kg * 4 + reg;
                int odd = x2 & 1;
                int xi = odd ? ((x2 + 1) >> 1) : (x2 >> 1);
                char* ab = smraw + (odd ? A2O : A2E);
                float v = fmaxf(acc[mt][reg], 0.f);
                *(__hip_bfloat16*)(ab + (((q * 11 + row) * 9 + xi) * 8 + sub) * 2) = __float2bfloat16(v);
            }
        }
    }
    __syncthreads();

    // ---- conv3 + epilogue (R9-verbatim) ----
    {
        const int nt = wvu & 1;
        const bool two = wvu < 2;
        f32x4 c3a = (f32x4){0.f, 0.f, 0.f, 0.f};
        f32x4 c3b = (f32x4){0.f, 0.f, 0.f, 0.f};
        const int xb = m & 7, yb = m >> 3;
#pragma unroll
        for (int p = 0; p < 9; ++p) {
            int ky = p / 3, kx = p % 3;
            const char* arr = smraw + ((kx == 1) ? A2E : A2O);
            int xi3 = xb + (kx == 2);
#pragma unroll
            for (int h = 0; h < 2; ++h) {
                bshort8 B = *(const bshort8*)(w3b + (((nt * 9 + p) * 2 + h) * 64 + l) * 8);
                int q = h * 4 + kg;
                const char* base = arr + ((q * 11 + 2 * yb + ky) * 9 + xi3) * 16;
                if (two) {
                    bshort8 A0 = *(const bshort8*)(base);
                    c3a = __builtin_amdgcn_mfma_f32_16x16x32_bf16(A0, B, c3a, 0, 0, 0);
                    bshort8 A2 = *(const bshort8*)(base + 1152);
                    c3b = __builtin_amdgcn_mfma_f32_16x16x32_bf16(A2, B, c3b, 0, 0, 0);
                } else {
                    bshort8 A1 = *(const bshort8*)(base + 576);
                    c3a = __builtin_amdgcn_mfma_f32_16x16x32_bf16(A1, B, c3a, 0, 0, 0);
                }
            }
        }
        __syncthreads();
        float* sb = (float*)smraw;
        int oc = nt * 16 + m;
        float bv = b3[oc];
        int ob40 = oc * 40;
        if (two) {
#pragma unroll
            for (int reg = 0; reg < 4; ++reg) {
                sb[ob40 + kg * 4 + reg] = fmaxf(c3a[reg] + bv, 0.f);
                int px2 = 32 + kg * 4 + reg;
                if (px2 < 40) sb[ob40 + px2] = fmaxf(c3b[reg] + bv, 0.f);
            }
        } else {
#pragma unroll
            for (int reg = 0; reg < 4; ++reg)
                sb[ob40 + 16 + kg * 4 + reg] = fmaxf(c3a[reg] + bv, 0.f);
        }
        __syncthreads();
        for (int i = t; i < 1283; i += 256)
            seq[(long)img * 1283 + i] = (i < 1280) ? sb[i] : relpos[img * 3 + (i - 1280)];
    }
}

// ---------------------------------------------------------------------------
// Sensory (R9/R7-verbatim): pair-blocked, 256 blocks x 768 thr, 48KB LDS.
// ---------------------------------------------------------------------------
__global__ __launch_bounds__(768) void sensory_kernel(
    const float* __restrict__ sp, const float* __restrict__ seq,
    const float* __restrict__ iw, const float* __restrict__ ibias,
    float2* __restrict__ part) {
    const float4* P4 = (const float4*)sp;
    __shared__ __align__(16) char sbuf[49152];
    float*  IT  = (float*)sbuf;
    float2* red = (float2*)sbuf;
    const int t = threadIdx.x;
    const int pb = blockIdx.x * 8;

    for (int p = 0; p < 8; ++p)
        for (int k = t; k < 1283; k += 768)
            IT[k * 8 + p] = fmaf(seq[(long)(pb + p) * 1283 + k], iw[k], ibias[k]);
    __syncthreads();

    const int u = t % 48, kg = t / 48;
    float2 acc[8];
#pragma unroll
    for (int p = 0; p < 8; ++p) acc[p] = make_float2(0.f, 0.f);

#pragma unroll 2
    for (int i = 0; i < 81; ++i) {
        int k = kg + 16 * i;
        if (k < 1283) {
            float4 pv = P4[k * 48 + u];
            float4 Ia = *(const float4*)&IT[k * 8];
            float4 Ib = *(const float4*)&IT[k * 8 + 4];
            float r0 = __builtin_amdgcn_rcpf(1.f + __builtin_amdgcn_exp2f(fmaf(pv.x, Ia.x, pv.y)));
            float r1 = __builtin_amdgcn_rcpf(1.f + __builtin_amdgcn_exp2f(fmaf(pv.x, Ia.y, pv.y)));
            float r2 = __builtin_amdgcn_rcpf(1.f + __builtin_amdgcn_exp2f(fmaf(pv.x, Ia.z, pv.y)));
            float r3 = __builtin_amdgcn_rcpf(1.f + __builtin_amdgcn_exp2f(fmaf(pv.x, Ia.w, pv.y)));
            float r4 = __builtin_amdgcn_rcpf(1.f + __builtin_amdgcn_exp2f(fmaf(pv.x, Ib.x, pv.y)));
            float r5 = __builtin_amdgcn_rcpf(1.f + __builtin_amdgcn_exp2f(fmaf(pv.x, Ib.y, pv.y)));
            float r6 = __builtin_amdgcn_rcpf(1.f + __builtin_amdgcn_exp2f(fmaf(pv.x, Ib.z, pv.y)));
            float r7 = __builtin_amdgcn_rcpf(1.f + __builtin_amdgcn_exp2f(fmaf(pv.x, Ib.w, pv.y)));
            acc[0].x = fmaf(pv.z, r0, acc[0].x); acc[0].y = fmaf(pv.w, r0, acc[0].y);
            acc[1].x = fmaf(pv.z, r1, acc[1].x); acc[1].y = fmaf(pv.w, r1, acc[1].y);
            acc[2].x = fmaf(pv.z, r2, acc[2].x); acc[2].y = fmaf(pv.w, r2, acc[2].y);
            acc[3].x = fmaf(pv.z, r3, acc[3].x); acc[3].y = fmaf(pv.w, r3, acc[3].y);
            acc[4].x = fmaf(pv.z, r4, acc[4].x); acc[4].y = fmaf(pv.w, r4, acc[4].y);
            acc[5].x = fmaf(pv.z, r5, acc[5].x); acc[5].y = fmaf(pv.w, r5, acc[5].y);
            acc[6].x = fmaf(pv.z, r6, acc[6].x); acc[6].y = fmaf(pv.w, r6, acc[6].y);
            acc[7].x = fmaf(pv.z, r7, acc[7].x); acc[7].y = fmaf(pv.w, r7, acc[7].y);
        }
    }
    __syncthreads();
#pragma unroll
    for (int p = 0; p < 8; ++p) red[(kg * 8 + p) * 48 + u] = acc[p];
    __syncthreads();
    if (t < 384) {
        int p = t / 48, uu = t - p * 48;
        float sn = 0.f, sd = 0.f;
#pragma unroll
        for (int g = 0; g < 16; ++g) {
            float2 rr = red[(g * 8 + p) * 48 + uu];
            sn += rr.x; sd += rr.y;
        }
        part[(long)(pb + p) * 48 + uu] = make_float2(sn, sd);
    }
}

// ---------------------------------------------------------------------------
// Recurrent (R9-verbatim): 64 blocks x 512 thr, v in regs, 1 barrier/unfold.
// ---------------------------------------------------------------------------
__global__ __launch_bounds__(512) void recurrent_kernel(
    const float* __restrict__ rp, const float* __restrict__ cmglv,
    const float2* __restrict__ part,
    const float* __restrict__ out_w, const float* __restrict__ out_b,
    const float* __restrict__ head_w, const float* __restrict__ head_b,
    float* __restrict__ outp) {
    const float4* RP4 = (const float4*)rp;
    __shared__ float2 WL[32 * 48];
    __shared__ float2 red[2][8][64];
    __shared__ float ym[4];
    const int t = threadIdx.x, b = blockIdx.x;
    const int u = t & 63;
    const int jg = __builtin_amdgcn_readfirstlane(t >> 6);
    const int j0 = jg * 6;
    const bool uval = u < 48;
    float4 rpj[6];
#pragma unroll
    for (int jj = 0; jj < 6; ++jj) rpj[jj] = RP4[(j0 + jj) * 64 + u];
    for (int i = t; i < 1536; i += 512) WL[i] = part[(long)b * 1536 + i];
    float cmt = 0.f, gl = 0.f, glv = 0.f;
    if (uval) { cmt = cmglv[u]; gl = cmglv[64 + u]; glv = cmglv[128 + u]; }
    float ow = 0.f, ob = 0.f;
    if (jg == 0 && u < 4) { ow = out_w[u]; ob = out_b[u]; }
    __syncthreads();

    float vn = 0.f;
    float yacc = 0.f;
    int buf = 0;
    for (int s = 0; s < 32; ++s) {
        float2 wnd = uval ? WL[s * 48 + u] : make_float2(0.f, 0.f);
#pragma unroll 1
        for (int unf = 0; unf < 6; ++unf) {
            float pn = 0.f, pd = 0.f;
#pragma unroll
            for (int jj = 0; jj < 6; ++jj) {
                float vj = __shfl(vn, j0 + jj, 64);
                float r = __builtin_amdgcn_rcpf(1.f + __builtin_amdgcn_exp2f(fmaf(rpj[jj].x, vj, rpj[jj].y)));
                pn = fmaf(rpj[jj].z, r, pn);
                pd = fmaf(rpj[jj].w, r, pd);
            }
            red[buf][jg][u] = make_float2(pn, pd);
            __syncthreads();
            float sn = 0.f, sd = 0.f;
#pragma unroll
            for (int g = 0; g < 8; ++g) {
                float2 rr = red[buf][g][u];
                sn += rr.x; sd += rr.y;
            }
            float num = fmaf(cmt, vn, glv) + sn + wnd.x;
            float den = cmt + gl + sd + wnd.y;
            vn = uval ? num / (den + 1e-8f) : 0.f;
            buf ^= 1;
        }
        if (jg == 0 && u < 4) yacc = fmaf(vn, ow, yacc) + ob;
    }
    if (jg == 0 && u < 4) ym[u] = yacc;
    __syncthreads();
    if (t < 2) {
        const float inv = 1.f / 32.f;
        float o = ym[0] * inv * head_w[t] + ym[1] * inv * head_w[2 + t] +
                  ym[2] * inv * head_w[4 + t] + ym[3] * inv * head_w[6 + t] + head_b[t];
        outp[b * 2 + t] = tanhf(o);
    }
}

extern "C" void kernel_launch(void* const* d_in, const int* in_sizes, int n_in,
                              void* d_out, int out_size, void* d_ws, size_t ws_size,
                              hipStream_t stream) {
    const float* depth      = (const float*)d_in[0];
    const float* relpos     = (const float*)d_in[1];
    const float* w1         = (const float*)d_in[2];
    const float* b1         = (const float*)d_in[3];
    const float* w2         = (const float*)d_in[4];
    const float* b2         = (const float*)d_in[5];
    const float* w3         = (const float*)d_in[6];
    const float* b3         = (const float*)d_in[7];
    const float* iw         = (const float*)d_in[8];
    const float* ibias      = (const float*)d_in[9];
    const float* sens_w     = (const float*)d_in[10];
    const float* sens_mu    = (const float*)d_in[11];
    const float* sens_sigma = (const float*)d_in[12];
    const float* sens_erev  = (const float*)d_in[13];
    const float* rec_w      = (const float*)d_in[14];
    const float* rec_mu     = (const float*)d_in[15];
    const float* rec_sigma  = (const float*)d_in[16];
    const float* rec_erev   = (const float*)d_in[17];
    const float* gleak      = (const float*)d_in[18];
    const float* vleak      = (const float*)d_in[19];
    const float* cm         = (const float*)d_in[20];
    const float* out_w      = (const float*)d_in[21];
    const float* out_b      = (const float*)d_in[22];
    const float* head_w     = (const float*)d_in[23];
    const float* head_b     = (const float*)d_in[24];
    const int*   sens_mask  = (const int*)d_in[25];
    const int*   rec_mask   = (const int*)d_in[26];

    float* ws  = (float*)d_ws;
    float* out = (float*)d_out;

    prep_kernel<<<477, 256, 0, stream>>>(sens_w, sens_mu, sens_sigma, sens_erev, sens_mask,
                                         rec_w, rec_mu, rec_sigma, rec_erev, rec_mask,
                                         gleak, vleak, cm, w2, w3, ws);
    cnn_kernel<<<2048, 256, 0, stream>>>(depth, relpos, w1, b1, b2, b3,
                                         (const __hip_bfloat16*)(ws + OFF_W2B),
                                         (const __hip_bfloat16*)(ws + OFF_W3B),
                                         ws + OFF_SEQ);
    sensory_kernel<<<256, 768, 0, stream>>>(ws + OFF_SP4, ws + OFF_SEQ, iw, ibias,
                                            (float2*)(ws + OFF_PART));
    recurrent_kernel<<<64, 512, 0, stream>>>(ws + OFF_RP4, ws + OFF_CM,
                                             (const float2*)(ws + OFF_PART),
                                             out_w, out_b, head_w, head_b, out);
}

// Round 12
// 294.747 us; speedup vs baseline: 1.2254x; 1.1596x over previous
//
#include <hip/hip_runtime.h>
#include <hip/hip_bf16.h>

// Shapes: B=64 S=32 H=40 W=64 ; conv1: 1->32 (20x32) ; conv2: 32->64 (10x16) ; conv3: 64->32 (5x8)
// SENS=1283 UNITS=48 MOTOR=4 NA=2 UNFOLDS=6

typedef __attribute__((ext_vector_type(8))) short bshort8;   // 8 bf16 (4 VGPR) MFMA frag
typedef __attribute__((ext_vector_type(4))) float f32x4;     // MFMA acc

// ---- workspace layout (float units) ----
constexpr long OFF_SEQ  = 0;                 // 2048*1283 = 2627584
constexpr long OFF_SP4  = 2627584;           // sensory params float4[1283*48] = 246336 fl
constexpr long OFF_RP4  = 2873920;           // rec params float4[48*64] = 12288 fl
constexpr long OFF_CM   = 2886208;           // cm_t(64), gl(64), gl*vleak(64)
constexpr long OFF_W2B  = 2886400;           // conv2 bf16 frags (K-repacked): 24576 bf16 = 12288 fl
constexpr long OFF_W3B  = 2898688;           // conv3 bf16 frags: 18432 bf16 = 9216 fl
constexpr long OFF_PART = 2907904;           // float2[2048*48] = 196608 fl
// end 3104512 fl = 12.42 MB

__device__ __forceinline__ float sp_(float x) {
    return fmaxf(x, 0.f) + log1pf(expf(-fabsf(x)));   // stable softplus
}

// ---------------------------------------------------------------------------
// prep (R11-verbatim). w2b K-repack: K=32 = (x1off 2) x (ic-local 16).
// ---------------------------------------------------------------------------
__global__ void prep_kernel(const float* __restrict__ sens_w, const float* __restrict__ sens_mu,
                            const float* __restrict__ sens_sigma, const float* __restrict__ sens_erev,
                            const int* __restrict__ sens_mask,
                            const float* __restrict__ rec_w, const float* __restrict__ rec_mu,
                            const float* __restrict__ rec_sigma, const float* __restrict__ rec_erev,
                            const int* __restrict__ rec_mask,
                            const float* __restrict__ gleak, const float* __restrict__ vleak,
                            const float* __restrict__ cm,
                            const float* __restrict__ w2, const float* __restrict__ w3,
                            float* __restrict__ ws) {
    const float L2E = 1.4426950408889634f;
    int i = blockIdx.x * 256 + threadIdx.x;
    if (i < 61584) {                       // sensory packed [k 1283][u 48]
        float m  = sens_mask[i] ? 1.f : 0.f;
        float sw = sp_(sens_w[i]) * m;
        float sg = sens_sigma[i], mu = sens_mu[i];
        ((float4*)(ws + OFF_SP4))[i] =
            make_float4(-sg * L2E, sg * mu * L2E, sw * sens_erev[i], sw);
    } else if (i < 64656) {                // recurrent: [j 48][u 64 padded]
        int q = i - 61584;
        int j = q >> 6, u = q & 63;
        float4 v = make_float4(0.f, 0.f, 0.f, 0.f);
        if (u < 48) {
            int idx = j * 48 + u;
            float m  = rec_mask[idx] ? 1.f : 0.f;
            float sw = sp_(rec_w[idx]) * m;
            float sg = rec_sigma[idx], mu = rec_mu[idx];
            v = make_float4(-sg * L2E, sg * mu * L2E, sw * rec_erev[idx], sw);
        }
        ((float4*)(ws + OFF_RP4))[q] = v;
    } else if (i < 64704) {
        int u = i - 64656;                 // u < 48
        float g = sp_(gleak[u]);
        ws[OFF_CM + u]       = sp_(cm[u]) * 6.f;
        ws[OFF_CM + 64 + u]  = g;
        ws[OFF_CM + 128 + u] = g * vleak[u];
    } else if (i < 89280) {                // w2b K-repacked frags (24576)
        int n = i - 64704;
        int j = n & 7, l = (n >> 3) & 63, t2 = n >> 9;   // t2 0..47
        int wv = t2 & 3;
        int r  = t2 >> 2;                  // 0..11 = (h*3+ky)*2+xp
        int xp = r & 1, hk = r >> 1;       // hk = h*3+ky
        int ky = hk % 3, h = hk / 3;
        int oc = wv * 16 + (l & 15);
        int kgB = l >> 4;
        int icl = (kgB & 1) * 8 + j;
        int ic = h * 16 + icl;
        int kx = 2 * xp + (kgB >> 1);
        float val = (kx == 3) ? 0.f : w2[((oc * 32 + ic) * 3 + ky) * 3 + kx];
        ((__hip_bfloat16*)(ws + OFF_W2B))[n] = __float2bfloat16(val);
    } else if (i < 107712) {               // w3b frags (unchanged mapping)
        int n = i - 89280;
        int j = n & 7, l = (n >> 3) & 63, t3 = n >> 9;
        int h = t3 & 1, u2 = t3 >> 1;
        int nt = u2 / 9, p = u2 % 9;
        int ky = p / 3, kx = p % 3;
        int oc = nt * 16 + (l & 15);
        int ic = h * 32 + (l >> 4) * 8 + j;
        ((__hip_bfloat16*)(ws + OFF_W3B))[n] =
            __float2bfloat16(w3[((oc * 64 + ic) * 3 + ky) * 3 + kx]);
    }
}

// ---------------------------------------------------------------------------
// Fused CNN, channel-split conv1/conv2 (27.6 KB LDS). R11-verbatim except
// __launch_bounds__ 5 -> 4: R11's (256,5) capped VGPRs at 48 and spilled the
// MFMA accumulators (FETCH 93MB/WRITE 206MB of scratch traffic). (256,4)
// gives a 128-VGPR budget: acc[10]=40 + Bh[6]=24 + locals fits, 4 blocks/CU.
// ---------------------------------------------------------------------------
#define IMGB 0
#define C1H  5424
#define A2E  0
#define A2O  12672
#define SMB  28272

__global__ __launch_bounds__(256, 4) void cnn_kernel(
    const float* __restrict__ depth, const float* __restrict__ relpos,
    const float* __restrict__ w1, const float* __restrict__ b1,
    const float* __restrict__ b2, const float* __restrict__ b3,
    const __hip_bfloat16* __restrict__ w2b, const __hip_bfloat16* __restrict__ w3b,
    float* __restrict__ seq) {
    __shared__ __align__(16) char smraw[SMB];
    const int t = threadIdx.x;
    const int img = blockIdx.x;
    const int l = t & 63;
    const int wvu = __builtin_amdgcn_readfirstlane(t >> 6);
    const int m = l & 15, kg = l >> 4;

    // ---- zero ENTIRE img+c1h region (pads persist through both passes) ----
    for (int i = t; i < 7068; i += 256) ((uint*)smraw)[i] = 0u;
    __syncthreads();
    for (int i = t; i < 1280; i += 256) {
        int pos = 2 * i;
        int h = pos >> 6, w = pos & 63;
        float2 d = *(const float2*)(depth + (long)img * 2560 + pos);
        __hip_bfloat162 pk = __float22bfloat162_rn(d);
        *(__hip_bfloat162*)(smraw + IMGB + ((h + 1) * 66 + (w + 2)) * 2) = pk;
    }
    __syncthreads();

    const __hip_bfloat16* imgp = (const __hip_bfloat16*)(smraw + IMGB);
    f32x4 acc[10];
    {
        float bias = b2[wvu * 16 + m];
#pragma unroll
        for (int mt = 0; mt < 10; ++mt) acc[mt] = (f32x4){bias, bias, bias, bias};
    }

#pragma unroll 1
    for (int h = 0; h < 2; ++h) {
        // ---- conv1 pass h: 16 oc (wave wvu -> 4 oc), 10 px/lane ----
        const int ocb = h * 16 + wvu * 4;      // uniform
        float wv4[4][9], bv4[4];
#pragma unroll
        for (int j = 0; j < 4; ++j) {
            bv4[j] = b1[ocb + j];
#pragma unroll
            for (int k = 0; k < 9; ++k) wv4[j][k] = w1[(ocb + j) * 9 + k];
        }
#pragma unroll 1
        for (int i = 0; i < 10; ++i) {
            int p = l + (i << 6);
            int y1 = p >> 5, x1 = p & 31;
            float xin[9];
#pragma unroll
            for (int ky = 0; ky < 3; ++ky)
#pragma unroll
                for (int kx = 0; kx < 3; ++kx)
                    xin[ky * 3 + kx] = __bfloat162float(imgp[(2 * y1 + ky) * 66 + 2 * x1 + kx + 1]);
            float o[4];
#pragma unroll
            for (int j = 0; j < 4; ++j) {
                float a = bv4[j];
#pragma unroll
                for (int k = 0; k < 9; ++k) a = fmaf(wv4[j][k], xin[k], a);
                o[j] = fmaxf(a, 0.f);
            }
            char* cb = smraw + C1H + (((y1 + 1) * 34) + (x1 + 1)) * 32 + wvu * 8;
            *(__hip_bfloat162*)cb       = __float22bfloat162_rn(make_float2(o[0], o[1]));
            *(__hip_bfloat162*)(cb + 4) = __float22bfloat162_rn(make_float2(o[2], o[3]));
        }
        // ---- conv2 K-half h ----
        bshort8 Bh[6];
#pragma unroll
        for (int f = 0; f < 6; ++f)
            Bh[f] = *(const bshort8*)(w2b + (((h * 6 + f) * 4 + wvu) * 64 + l) * 8);
        __syncthreads();   // c1h pass-h ready
#pragma unroll
        for (int ky = 0; ky < 3; ++ky) {
#pragma unroll
            for (int xp = 0; xp < 2; ++xp) {
                bshort8 Bp = Bh[ky * 2 + xp];
                const char* base = smraw + C1H + (ky * 34 + 2 * m + 2 * xp + (kg >> 1)) * 32 + (kg & 1) * 16;
#pragma unroll
                for (int mt = 0; mt < 10; ++mt) {
                    bshort8 A = *(const bshort8*)(base + mt * 2176);   // 2 rows * 34 cols * 32 B
                    acc[mt] = __builtin_amdgcn_mfma_f32_16x16x32_bf16(A, Bp, acc[mt], 0, 0, 0);
                }
            }
        }
        __syncthreads();   // reads done before next conv1 overwrite / a2 overlay
    }

    // ---- a2 overlay (R9-verbatim): full zero, barrier, write, barrier ----
    for (int i = t; i < 6336; i += 256) ((uint*)smraw)[i] = 0u;
    __syncthreads();
    {
        int oc = wvu * 16 + m;
        int q = oc >> 3, sub = oc & 7;
#pragma unroll
        for (int mt = 0; mt < 10; ++mt) {
            int row = mt + 1;
#pragma unroll
            for (int reg = 0; reg < 4; ++reg) {
                int x2 = kg * 4 + reg;
                int odd = x2 & 1;
                int xi = odd ? ((x2 + 1) >> 1) : (x2 >> 1);
                char* ab = smraw + (odd ? A2O : A2E);
                float v = fmaxf(acc[mt][reg], 0.f);
                *(__hip_bfloat16*)(ab + (((q * 11 + row) * 9 + xi) * 8 + sub) * 2) = __float2bfloat16(v);
            }
        }
    }
    __syncthreads();

    // ---- conv3 + epilogue (R9-verbatim) ----
    {
        const int nt = wvu & 1;
        const bool two = wvu < 2;
        f32x4 c3a = (f32x4){0.f, 0.f, 0.f, 0.f};
        f32x4 c3b = (f32x4){0.f, 0.f, 0.f, 0.f};
        const int xb = m & 7, yb = m >> 3;
#pragma unroll
        for (int p = 0; p < 9; ++p) {
            int ky = p / 3, kx = p % 3;
            const char* arr = smraw + ((kx == 1) ? A2E : A2O);
            int xi3 = xb + (kx == 2);
#pragma unroll
            for (int h = 0; h < 2; ++h) {
                bshort8 B = *(const bshort8*)(w3b + (((nt * 9 + p) * 2 + h) * 64 + l) * 8);
                int q = h * 4 + kg;
                const char* base = arr + ((q * 11 + 2 * yb + ky) * 9 + xi3) * 16;
                if (two) {
                    bshort8 A0 = *(const bshort8*)(base);
                    c3a = __builtin_amdgcn_mfma_f32_16x16x32_bf16(A0, B, c3a, 0, 0, 0);
                    bshort8 A2 = *(const bshort8*)(base + 1152);
                    c3b = __builtin_amdgcn_mfma_f32_16x16x32_bf16(A2, B, c3b, 0, 0, 0);
                } else {
                    bshort8 A1 = *(const bshort8*)(base + 576);
                    c3a = __builtin_amdgcn_mfma_f32_16x16x32_bf16(A1, B, c3a, 0, 0, 0);
                }
            }
        }
        __syncthreads();
        float* sb = (float*)smraw;
        int oc = nt * 16 + m;
        float bv = b3[oc];
        int ob40 = oc * 40;
        if (two) {
#pragma unroll
            for (int reg = 0; reg < 4; ++reg) {
                sb[ob40 + kg * 4 + reg] = fmaxf(c3a[reg] + bv, 0.f);
                int px2 = 32 + kg * 4 + reg;
                if (px2 < 40) sb[ob40 + px2] = fmaxf(c3b[reg] + bv, 0.f);
            }
        } else {
#pragma unroll
            for (int reg = 0; reg < 4; ++reg)
                sb[ob40 + 16 + kg * 4 + reg] = fmaxf(c3a[reg] + bv, 0.f);
        }
        __syncthreads();
        for (int i = t; i < 1283; i += 256)
            seq[(long)img * 1283 + i] = (i < 1280) ? sb[i] : relpos[img * 3 + (i - 1280)];
    }
}

// ---------------------------------------------------------------------------
// Sensory (R9/R7-verbatim): pair-blocked, 256 blocks x 768 thr, 48KB LDS.
// ---------------------------------------------------------------------------
__global__ __launch_bounds__(768) void sensory_kernel(
    const float* __restrict__ sp, const float* __restrict__ seq,
    const float* __restrict__ iw, const float* __restrict__ ibias,
    float2* __restrict__ part) {
    const float4* P4 = (const float4*)sp;
    __shared__ __align__(16) char sbuf[49152];
    float*  IT  = (float*)sbuf;
    float2* red = (float2*)sbuf;
    const int t = threadIdx.x;
    const int pb = blockIdx.x * 8;

    for (int p = 0; p < 8; ++p)
        for (int k = t; k < 1283; k += 768)
            IT[k * 8 + p] = fmaf(seq[(long)(pb + p) * 1283 + k], iw[k], ibias[k]);
    __syncthreads();

    const int u = t % 48, kg = t / 48;
    float2 acc[8];
#pragma unroll
    for (int p = 0; p < 8; ++p) acc[p] = make_float2(0.f, 0.f);

#pragma unroll 2
    for (int i = 0; i < 81; ++i) {
        int k = kg + 16 * i;
        if (k < 1283) {
            float4 pv = P4[k * 48 + u];
            float4 Ia = *(const float4*)&IT[k * 8];
            float4 Ib = *(const float4*)&IT[k * 8 + 4];
            float r0 = __builtin_amdgcn_rcpf(1.f + __builtin_amdgcn_exp2f(fmaf(pv.x, Ia.x, pv.y)));
            float r1 = __builtin_amdgcn_rcpf(1.f + __builtin_amdgcn_exp2f(fmaf(pv.x, Ia.y, pv.y)));
            float r2 = __builtin_amdgcn_rcpf(1.f + __builtin_amdgcn_exp2f(fmaf(pv.x, Ia.z, pv.y)));
            float r3 = __builtin_amdgcn_rcpf(1.f + __builtin_amdgcn_exp2f(fmaf(pv.x, Ia.w, pv.y)));
            float r4 = __builtin_amdgcn_rcpf(1.f + __builtin_amdgcn_exp2f(fmaf(pv.x, Ib.x, pv.y)));
            float r5 = __builtin_amdgcn_rcpf(1.f + __builtin_amdgcn_exp2f(fmaf(pv.x, Ib.y, pv.y)));
            float r6 = __builtin_amdgcn_rcpf(1.f + __builtin_amdgcn_exp2f(fmaf(pv.x, Ib.z, pv.y)));
            float r7 = __builtin_amdgcn_rcpf(1.f + __builtin_amdgcn_exp2f(fmaf(pv.x, Ib.w, pv.y)));
            acc[0].x = fmaf(pv.z, r0, acc[0].x); acc[0].y = fmaf(pv.w, r0, acc[0].y);
            acc[1].x = fmaf(pv.z, r1, acc[1].x); acc[1].y = fmaf(pv.w, r1, acc[1].y);
            acc[2].x = fmaf(pv.z, r2, acc[2].x); acc[2].y = fmaf(pv.w, r2, acc[2].y);
            acc[3].x = fmaf(pv.z, r3, acc[3].x); acc[3].y = fmaf(pv.w, r3, acc[3].y);
            acc[4].x = fmaf(pv.z, r4, acc[4].x); acc[4].y = fmaf(pv.w, r4, acc[4].y);
            acc[5].x = fmaf(pv.z, r5, acc[5].x); acc[5].y = fmaf(pv.w, r5, acc[5].y);
            acc[6].x = fmaf(pv.z, r6, acc[6].x); acc[6].y = fmaf(pv.w, r6, acc[6].y);
            acc[7].x = fmaf(pv.z, r7, acc[7].x); acc[7].y = fmaf(pv.w, r7, acc[7].y);
        }
    }
    __syncthreads();
#pragma unroll
    for (int p = 0; p < 8; ++p) red[(kg * 8 + p) * 48 + u] = acc[p];
    __syncthreads();
    if (t < 384) {
        int p = t / 48, uu = t - p * 48;
        float sn = 0.f, sd = 0.f;
#pragma unroll
        for (int g = 0; g < 16; ++g) {
            float2 rr = red[(g * 8 + p) * 48 + uu];
            sn += rr.x; sd += rr.y;
        }
        part[(long)(pb + p) * 48 + uu] = make_float2(sn, sd);
    }
}

// ---------------------------------------------------------------------------
// Recurrent (R9-verbatim): 64 blocks x 512 thr, v in regs, 1 barrier/unfold.
// ---------------------------------------------------------------------------
__global__ __launch_bounds__(512) void recurrent_kernel(
    const float* __restrict__ rp, const float* __restrict__ cmglv,
    const float2* __restrict__ part,
    const float* __restrict__ out_w, const float* __restrict__ out_b,
    const float* __restrict__ head_w, const float* __restrict__ head_b,
    float* __restrict__ outp) {
    const float4* RP4 = (const float4*)rp;
    __shared__ float2 WL[32 * 48];
    __shared__ float2 red[2][8][64];
    __shared__ float ym[4];
    const int t = threadIdx.x, b = blockIdx.x;
    const int u = t & 63;
    const int jg = __builtin_amdgcn_readfirstlane(t >> 6);
    const int j0 = jg * 6;
    const bool uval = u < 48;
    float4 rpj[6];
#pragma unroll
    for (int jj = 0; jj < 6; ++jj) rpj[jj] = RP4[(j0 + jj) * 64 + u];
    for (int i = t; i < 1536; i += 512) WL[i] = part[(long)b * 1536 + i];
    float cmt = 0.f, gl = 0.f, glv = 0.f;
    if (uval) { cmt = cmglv[u]; gl = cmglv[64 + u]; glv = cmglv[128 + u]; }
    float ow = 0.f, ob = 0.f;
    if (jg == 0 && u < 4) { ow = out_w[u]; ob = out_b[u]; }
    __syncthreads();

    float vn = 0.f;
    float yacc = 0.f;
    int buf = 0;
    for (int s = 0; s < 32; ++s) {
        float2 wnd = uval ? WL[s * 48 + u] : make_float2(0.f, 0.f);
#pragma unroll 1
        for (int unf = 0; unf < 6; ++unf) {
            float pn = 0.f, pd = 0.f;
#pragma unroll
            for (int jj = 0; jj < 6; ++jj) {
                float vj = __shfl(vn, j0 + jj, 64);
                float r = __builtin_amdgcn_rcpf(1.f + __builtin_amdgcn_exp2f(fmaf(rpj[jj].x, vj, rpj[jj].y)));
                pn = fmaf(rpj[jj].z, r, pn);
                pd = fmaf(rpj[jj].w, r, pd);
            }
            red[buf][jg][u] = make_float2(pn, pd);
            __syncthreads();
            float sn = 0.f, sd = 0.f;
#pragma unroll
            for (int g = 0; g < 8; ++g) {
                float2 rr = red[buf][g][u];
                sn += rr.x; sd += rr.y;
            }
            float num = fmaf(cmt, vn, glv) + sn + wnd.x;
            float den = cmt + gl + sd + wnd.y;
            vn = uval ? num / (den + 1e-8f) : 0.f;
            buf ^= 1;
        }
        if (jg == 0 && u < 4) yacc = fmaf(vn, ow, yacc) + ob;
    }
    if (jg == 0 && u < 4) ym[u] = yacc;
    __syncthreads();
    if (t < 2) {
        const float inv = 1.f / 32.f;
        float o = ym[0] * inv * head_w[t] + ym[1] * inv * head_w[2 + t] +
                  ym[2] * inv * head_w[4 + t] + ym[3] * inv * head_w[6 + t] + head_b[t];
        outp[b * 2 + t] = tanhf(o);
    }
}

extern "C" void kernel_launch(void* const* d_in, const int* in_sizes, int n_in,
                              void* d_out, int out_size, void* d_ws, size_t ws_size,
                              hipStream_t stream) {
    const float* depth      = (const float*)d_in[0];
    const float* relpos     = (const float*)d_in[1];
    const float* w1         = (const float*)d_in[2];
    const float* b1         = (const float*)d_in[3];
    const float* w2         = (const float*)d_in[4];
    const float* b2         = (const float*)d_in[5];
    const float* w3         = (const float*)d_in[6];
    const float* b3         = (const float*)d_in[7];
    const float* iw         = (const float*)d_in[8];
    const float* ibias      = (const float*)d_in[9];
    const float* sens_w     = (const float*)d_in[10];
    const float* sens_mu    = (const float*)d_in[11];
    const float* sens_sigma = (const float*)d_in[12];
    const float* sens_erev  = (const float*)d_in[13];
    const float* rec_w      = (const float*)d_in[14];
    const float* rec_mu     = (const float*)d_in[15];
    const float* rec_sigma  = (const float*)d_in[16];
    const float* rec_erev   = (const float*)d_in[17];
    const float* gleak      = (const float*)d_in[18];
    const float* vleak      = (const float*)d_in[19];
    const float* cm         = (const float*)d_in[20];
    const float* out_w      = (const float*)d_in[21];
    const float* out_b      = (const float*)d_in[22];
    const float* head_w     = (const float*)d_in[23];
    const float* head_b     = (const float*)d_in[24];
    const int*   sens_mask  = (const int*)d_in[25];
    const int*   rec_mask   = (const int*)d_in[26];

    float* ws  = (float*)d_ws;
    float* out = (float*)d_out;

    prep_kernel<<<477, 256, 0, stream>>>(sens_w, sens_mu, sens_sigma, sens_erev, sens_mask,
                                         rec_w, rec_mu, rec_sigma, rec_erev, rec_mask,
                                         gleak, vleak, cm, w2, w3, ws);
    cnn_kernel<<<2048, 256, 0, stream>>>(depth, relpos, w1, b1, b2, b3,
                                         (const __hip_bfloat16*)(ws + OFF_W2B),
                                         (const __hip_bfloat16*)(ws + OFF_W3B),
                                         ws + OFF_SEQ);
    sensory_kernel<<<256, 768, 0, stream>>>(ws + OFF_SP4, ws + OFF_SEQ, iw, ibias,
                                            (float2*)(ws + OFF_PART));
    recurrent_kernel<<<64, 512, 0, stream>>>(ws + OFF_RP4, ws + OFF_CM,
                                             (const float2*)(ws + OFF_PART),
                                             out_w, out_b, head_w, head_b, out);
}